// Round 7
// baseline (25852.551 us; speedup 1.0000x reference)
//
#include <hip/hip_runtime.h>
#include <hip/hip_bf16.h>
#include <stdint.h>

#define BATCH 64
#define SEQ   2048
#define HID   1024
#define EDIM  2048   // 2*HID

#define BM 128        // rows per block
#define BK 16         // k per step (2 granules)
#define KSTEPS (EDIM / BK)   // 128
// LDS: B dbuf 2x32KB + A dbuf 2x4KB + cov 512B + sred 4KB = 78336 B -> 2 blocks/CU
#define SMEM_BYTES 78336

typedef __bf16 bf16x8 __attribute__((ext_vector_type(8)));
typedef float  f32x16 __attribute__((ext_vector_type(16)));
typedef float  f32x4v __attribute__((ext_vector_type(4)));

__device__ __forceinline__ unsigned short f2bf(float x) {
    __hip_bfloat16 h = __float2bfloat16(x);
    return __builtin_bit_cast(unsigned short, h);
}

__device__ __forceinline__ uint4 pack8(f32x4v f0, f32x4v f1) {
    uint4 r;
    r.x = (unsigned)f2bf(f0.x) | ((unsigned)f2bf(f0.y) << 16);
    r.y = (unsigned)f2bf(f0.z) | ((unsigned)f2bf(f0.w) << 16);
    r.z = (unsigned)f2bf(f1.x) | ((unsigned)f2bf(f1.y) << 16);
    r.w = (unsigned)f2bf(f1.z) | ((unsigned)f2bf(f1.w) << 16);
    return r;
}

__device__ __forceinline__ void gload16(const void* g, void* l) {
    __builtin_amdgcn_global_load_lds(
        (const __attribute__((address_space(1))) void*)g,
        (__attribute__((address_space(3))) void*)l, 16, 0, 0);
}

__device__ __forceinline__ f32x4v ntload4(const float* p) {
    return __builtin_nontemporal_load((const f32x4v*)p);
}

// A-tile byte address in one 4KB buffer: [g][row swizzled] 16B chunks
__device__ __forceinline__ int a_off(int row, int g) {
    return g * 2048 + ((row ^ (g << 3)) << 4);
}

// ---------------- prep: W_h (EDIM x HID fp32) -> Wt bf16 granule-major:
// element (h,e) at Wt[(e>>3)*8192 + h*8 + (e&7)]  (per-granule 16KB h-contiguous)
__global__ void wh_transpose_kernel(const float* __restrict__ Wh,
                                    unsigned short* __restrict__ Wt) {
    __shared__ float tile[32][33];
    int bx = blockIdx.x & 63;    // e-tile
    int by = blockIdx.x >> 6;    // h-tile
    int e0 = bx * 32, h0 = by * 32;
    int tx = threadIdx.x & 31, ty = threadIdx.x >> 5;   // 32 x 8
    #pragma unroll
    for (int i = 0; i < 4; ++i)
        tile[ty + 8 * i][tx] = Wh[(size_t)(e0 + ty + 8 * i) * HID + h0 + tx];
    __syncthreads();
    if (ty < 4) {
        uint4 wv;
        unsigned short* ws = (unsigned short*)&wv;
        #pragma unroll
        for (int j = 0; j < 8; ++j) ws[j] = f2bf(tile[ty * 8 + j][tx]);
        *(uint4*)&Wt[(size_t)((e0 >> 3) + ty) * 8192 + (size_t)(h0 + tx) * 8] = wv;
    }
}

// ---------------- prep: dec_proj = decoder_hidden @ W_d  (fp32, (B,HID))
__global__ void dec_proj_kernel(const float* __restrict__ dec,
                                const float* __restrict__ Wd,
                                float* __restrict__ dp) {
    int gid = blockIdx.x * 256 + threadIdx.x;
    int b = gid >> 10, h = gid & 1023;
    const float* dr = dec + b * HID;
    float acc = 0.f;
    #pragma unroll 4
    for (int k = 0; k < HID; ++k) acc = fmaf(dr[k], Wd[(size_t)k * HID + h], acc);
    dp[gid] = acc;
}

#define MFMA32(a, bfv, c) __builtin_amdgcn_mfma_f32_32x32x16_bf16(a, bfv, c, 0, 0, 0)

// ---------------- main fused scores kernel: 128 rows x full N=1024, 16 waves,
// BK=16, 2 blocks/CU (independent-block overlap per m114), A read exactly once
__global__ __launch_bounds__(1024, 8) void scores_kernel(
    const float* __restrict__ enc, const float* __restrict__ cov,
    const unsigned short* __restrict__ Wt, const float* __restrict__ dp,
    const float* __restrict__ Wc, const float* __restrict__ vv,
    float* __restrict__ scores)
{
    extern __shared__ char smem[];
    unsigned short* BlS = (unsigned short*)smem;     // 2 bufs x 16384 shorts (32KB)
    char*  AlB   = smem + 65536;                     // 2 bufs x 4096 B
    float* cov_s = (float*)(smem + 73728);           // 128 floats
    float* sred  = (float*)(smem + 74240);           // 128 x 8 floats

    const int tid  = threadIdx.x;
    const int lane = tid & 63;
    const int wid  = tid >> 6;       // 0..15
    const int wm   = wid >> 3;       // 0..1 : 64-row half
    const int wn   = wid & 7;        // 0..7 : 128-col slice
    const int l31  = lane & 31;
    const int hi   = lane >> 5;

    const int b  = blockIdx.x >> 4;            // 1024 blocks = 64 b x 16 s-tiles
    const int s0 = (blockIdx.x & 15) * BM;

    const float* Abase = enc + (size_t)(b * SEQ + s0) * EDIM;

    // A staging: 256 threads (tid%4==0), one (row, granule) 16B pack each
    const bool astage = (tid & 3) == 0;
    const int au   = tid >> 2;                 // 0..255
    const int arow = au >> 1;                  // 0..127
    const int ag   = au & 1;                   // granule 0/1

    f32x16 acc[2][4];
    #pragma unroll
    for (int mi = 0; mi < 2; ++mi)
        #pragma unroll
        for (int nj = 0; nj < 4; ++nj)
            #pragma unroll
            for (int r = 0; r < 16; ++r) acc[mi][nj][r] = 0.f;

    if (tid < BM) cov_s[tid] = cov[b * SEQ + s0 + tid];

    // prologue: stage k-step 0 into buffer 0
    {
        const unsigned short* bs = Wt + (size_t)tid * 8;
        gload16(bs,        BlS + tid * 8);
        gload16(bs + 8192, BlS + 8192 + tid * 8);
        if (astage) {
            const float* ap = Abase + (size_t)arow * EDIM + ag * 8;
            *(uint4*)(AlB + a_off(arow, ag)) = pack8(ntload4(ap), ntload4(ap + 4));
        }
    }
    __syncthreads();

    for (int kk = 0; kk < KSTEPS; ++kk) {
        const int cur = kk & 1, nxt = cur ^ 1;
        const unsigned short* Bcur = BlS + cur * 16384;
        const char* Acur = AlB + cur * 4096;
        f32x4v a0n, a1n;

        if (kk + 1 < KSTEPS) {
            // next B tile: 32KB contiguous (2 granules) of Wt -> linear LDS
            const unsigned short* bs = Wt + (size_t)(kk + 1) * 16384 + (size_t)tid * 8;
            gload16(bs,        BlS + nxt * 16384 + tid * 8);
            gload16(bs + 8192, BlS + nxt * 16384 + 8192 + tid * 8);
            if (astage) {   // next A reg loads (nontemporal: keep B L2-resident)
                const float* ap = Abase + (size_t)arow * EDIM + (kk + 1) * BK + ag * 8;
                a0n = ntload4(ap); a1n = ntload4(ap + 4);
            }
        }

        bf16x8 afr[2], bfr[4];
        #pragma unroll
        for (int mi = 0; mi < 2; ++mi)
            afr[mi] = *(const bf16x8*)(Acur + a_off(wm * 64 + mi * 32 + l31, hi));
        #pragma unroll
        for (int nj = 0; nj < 4; ++nj)
            bfr[nj] = *(const bf16x8*)(Bcur + (size_t)hi * 8192 +
                                       (size_t)(wn * 128 + nj * 32 + l31) * 8);
        #pragma unroll
        for (int mi = 0; mi < 2; ++mi)
            #pragma unroll
            for (int nj = 0; nj < 4; ++nj)
                acc[mi][nj] = MFMA32(afr[mi], bfr[nj], acc[mi][nj]);

        if (kk + 1 < KSTEPS && astage)
            *(uint4*)(AlB + nxt * 4096 + a_off(arow, ag)) = pack8(a0n, a1n);
        __syncthreads();
    }

    // epilogue: + dec_proj + cov*W_c -> tanh -> * v, reduce over H
    float dv[4], wcv[4], vvv[4];
    #pragma unroll
    for (int nj = 0; nj < 4; ++nj) {
        const int h = wn * 128 + nj * 32 + l31;
        dv[nj]  = dp[b * HID + h];
        wcv[nj] = Wc[h];
        vvv[nj] = vv[h];
    }
    #pragma unroll
    for (int mi = 0; mi < 2; ++mi) {
        #pragma unroll
        for (int r = 0; r < 16; ++r) {
            const int row = wm * 64 + mi * 32 + (r & 3) + 8 * (r >> 2) + 4 * hi;
            const float cv = cov_s[row];
            float x = 0.f;
            #pragma unroll
            for (int nj = 0; nj < 4; ++nj) {
                float pre = acc[mi][nj][r] + dv[nj] + cv * wcv[nj];
                float pc = fminf(pre, 20.0f);       // tanh(20)==1 in fp32
                float e2 = __expf(2.0f * pc);
                x = fmaf((e2 - 1.0f) / (e2 + 1.0f), vvv[nj], x);
            }
            x += __shfl_xor(x, 1);
            x += __shfl_xor(x, 2);
            x += __shfl_xor(x, 4);
            x += __shfl_xor(x, 8);
            x += __shfl_xor(x, 16);
            if (l31 == 0) sred[row * 8 + wn] = x;
        }
    }
    __syncthreads();
    if (tid < BM) {
        float s = 0.f;
        #pragma unroll
        for (int w = 0; w < 8; ++w) s += sred[tid * 8 + w];
        scores[b * SEQ + s0 + tid] = s;
    }
}

// ---------------- softmax + coverage_new
__global__ void softmax_kernel(const float* __restrict__ scores,
                               const int* __restrict__ mask,
                               const float* __restrict__ cov,
                               float* __restrict__ out)
{
    __shared__ float red[8];
    int b = blockIdx.x, tid = threadIdx.x;   // 256 threads
    float vals[8];
    float mx = -1e30f;
    #pragma unroll
    for (int i = 0; i < 8; ++i) {
        int s = tid + i * 256;
        float sc = scores[b * SEQ + s];
        sc = (mask[b * SEQ + s] == 0) ? -10000.0f : sc;
        vals[i] = sc;
        mx = fmaxf(mx, sc);
    }
    for (int m = 1; m < 64; m <<= 1) mx = fmaxf(mx, __shfl_xor(mx, m));
    if ((tid & 63) == 0) red[tid >> 6] = mx;
    __syncthreads();
    mx = fmaxf(fmaxf(red[0], red[1]), fmaxf(red[2], red[3]));
    float sum = 0.f;
    #pragma unroll
    for (int i = 0; i < 8; ++i) { vals[i] = __expf(vals[i] - mx); sum += vals[i]; }
    for (int m = 1; m < 64; m <<= 1) sum += __shfl_xor(sum, m);
    if ((tid & 63) == 0) red[4 + (tid >> 6)] = sum;
    __syncthreads();
    sum = red[4] + red[5] + red[6] + red[7];
    float inv = 1.0f / sum;
    float* attn = out + BATCH * EDIM;
    float* covn = attn + BATCH * SEQ;
    #pragma unroll
    for (int i = 0; i < 8; ++i) {
        int s = tid + i * 256;
        float w = vals[i] * inv;
        attn[b * SEQ + s] = w;
        covn[b * SEQ + s] = cov[b * SEQ + s] + w;
    }
}

// ---------------- context partials: (b, e-slice, s-chunk) -> cpart
__global__ void context_partial_kernel(const float* __restrict__ enc,
                                       const float* __restrict__ attn,
                                       float* __restrict__ cpart)
{
    __shared__ float w_s[512];
    int bid = blockIdx.x;
    int sc = bid & 3;            // S-chunk of 512
    int e0 = ((bid >> 2) & 7) * 256;
    int b  = bid >> 5;
    int tid = threadIdx.x;
    w_s[tid] = attn[b * SEQ + sc * 512 + tid];
    w_s[tid + 256] = attn[b * SEQ + sc * 512 + 256 + tid];
    __syncthreads();
    const float* ep = enc + ((size_t)b * SEQ + sc * 512) * EDIM + e0 + tid;
    float acc = 0.f;
    #pragma unroll 8
    for (int s = 0; s < 512; ++s)
        acc = fmaf(w_s[s], __builtin_nontemporal_load(ep + (size_t)s * EDIM), acc);
    cpart[((size_t)sc * BATCH + b) * EDIM + e0 + tid] = acc;
}

__global__ void ctx_reduce_kernel(const float* __restrict__ cpart,
                                  float* __restrict__ ctx)
{
    int idx = blockIdx.x * 256 + threadIdx.x;     // 0 .. B*EDIM
    float s = cpart[idx] + cpart[BATCH * EDIM + idx] +
              cpart[2 * BATCH * EDIM + idx] + cpart[3 * BATCH * EDIM + idx];
    ctx[idx] = s;
}

extern "C" void kernel_launch(void* const* d_in, const int* in_sizes, int n_in,
                              void* d_out, int out_size, void* d_ws, size_t ws_size,
                              hipStream_t stream) {
    const float* dec  = (const float*)d_in[0];
    const float* enc  = (const float*)d_in[1];
    const float* cov  = (const float*)d_in[2];
    const int*   mask = (const int*)d_in[3];
    const float* Wh   = (const float*)d_in[4];
    const float* Wd   = (const float*)d_in[5];
    const float* Wc   = (const float*)d_in[6];
    const float* v    = (const float*)d_in[7];
    float* out = (float*)d_out;

    unsigned short* Wt = (unsigned short*)d_ws;                        // 4 MiB bf16
    float* dp     = (float*)((char*)d_ws + (size_t)HID * EDIM * 2);    // 256 KiB
    float* scores = dp + BATCH * HID;                                  // 512 KiB
    float* cpart  = scores + BATCH * SEQ;                              // 2 MiB

    (void)hipFuncSetAttribute((const void*)scores_kernel,
                              hipFuncAttributeMaxDynamicSharedMemorySize, SMEM_BYTES);

    wh_transpose_kernel<<<dim3(64 * 32), dim3(256), 0, stream>>>(Wh, Wt);
    dec_proj_kernel<<<dim3(BATCH * HID / 256), dim3(256), 0, stream>>>(dec, Wd, dp);
    scores_kernel<<<dim3(BATCH * (SEQ / BM)), dim3(1024), SMEM_BYTES, stream>>>(
        enc, cov, Wt, dp, Wc, v, scores);
    softmax_kernel<<<dim3(BATCH), dim3(256), 0, stream>>>(scores, mask, cov, out);
    context_partial_kernel<<<dim3(BATCH * 8 * 4), dim3(256), 0, stream>>>(
        enc, out + BATCH * EDIM, cpart);
    ctx_reduce_kernel<<<dim3(BATCH * EDIM / 256), dim3(256), 0, stream>>>(cpart, out);
}

// Round 9
// 1063.422 us; speedup vs baseline: 24.3107x; 24.3107x over previous
//
#include <hip/hip_runtime.h>
#include <hip/hip_bf16.h>
#include <stdint.h>

#define BATCH 64
#define SEQ   2048
#define HID   1024
#define EDIM  2048   // 2*HID

#define BM 64         // rows per block
#define BN 512        // cols per block (n-split = 2)
#define BK 32
#define KSTEPS (EDIM / BK)   // 64
#define BS (BATCH * SEQ)
// LDS: B dbuf 2x32KB + A dbuf 2x4KB + cov 256B + sred 1KB = 74.3KB -> 2 blocks/CU
#define SMEM_BYTES 76032

typedef __bf16 bf16x8 __attribute__((ext_vector_type(8)));
typedef float  f32x4a __attribute__((ext_vector_type(4)));

__device__ __forceinline__ unsigned short f2bf(float x) {
    __hip_bfloat16 h = __float2bfloat16(x);
    return __builtin_bit_cast(unsigned short, h);
}

__device__ __forceinline__ uint4 pack8(f32x4a f0, f32x4a f1) {
    uint4 r;
    r.x = (unsigned)f2bf(f0.x) | ((unsigned)f2bf(f0.y) << 16);
    r.y = (unsigned)f2bf(f0.z) | ((unsigned)f2bf(f0.w) << 16);
    r.z = (unsigned)f2bf(f1.x) | ((unsigned)f2bf(f1.y) << 16);
    r.w = (unsigned)f2bf(f1.z) | ((unsigned)f2bf(f1.w) << 16);
    return r;
}

__device__ __forceinline__ void gload16(const void* g, void* l) {
    __builtin_amdgcn_global_load_lds(
        (const __attribute__((address_space(1))) void*)g,
        (__attribute__((address_space(3))) void*)l, 16, 0, 0);
}

__device__ __forceinline__ f32x4a ntload4(const float* p) {
    return __builtin_nontemporal_load((const f32x4a*)p);
}

// A-tile LDS byte addr: 64 rows x 64B, granule slot XOR-swizzled -> ~2-way max
__device__ __forceinline__ int a_addr(int row, int g) {
    int slot = g ^ ((row & 3) ^ ((row >> 2) & 3));
    return (row << 6) + (slot << 4);
}

// ---------------- prep: W_h (EDIM x HID fp32) -> Wt bf16 granule-major:
// element (h,e) at Wt[(e>>3)*8192 + h*8 + (e&7)]  (per-granule 16KB h-contiguous)
__global__ void wh_transpose_kernel(const float* __restrict__ Wh,
                                    unsigned short* __restrict__ Wt) {
    __shared__ float tile[32][33];
    int bx = blockIdx.x & 63;    // e-tile
    int by = blockIdx.x >> 6;    // h-tile
    int e0 = bx * 32, h0 = by * 32;
    int tx = threadIdx.x & 31, ty = threadIdx.x >> 5;   // 32 x 8
    #pragma unroll
    for (int i = 0; i < 4; ++i)
        tile[ty + 8 * i][tx] = Wh[(size_t)(e0 + ty + 8 * i) * HID + h0 + tx];
    __syncthreads();
    if (ty < 4) {
        uint4 wv;
        unsigned short* ws = (unsigned short*)&wv;
        #pragma unroll
        for (int j = 0; j < 8; ++j) ws[j] = f2bf(tile[ty * 8 + j][tx]);
        *(uint4*)&Wt[(size_t)((e0 >> 3) + ty) * 8192 + (size_t)(h0 + tx) * 8] = wv;
    }
}

// ---------------- prep: dec_proj = decoder_hidden @ W_d  (fp32, (B,HID))
__global__ void dec_proj_kernel(const float* __restrict__ dec,
                                const float* __restrict__ Wd,
                                float* __restrict__ dp) {
    int gid = blockIdx.x * 256 + threadIdx.x;
    int b = gid >> 10, h = gid & 1023;
    const float* dr = dec + b * HID;
    float acc = 0.f;
    #pragma unroll 4
    for (int k = 0; k < HID; ++k) acc = fmaf(dr[k], Wd[(size_t)k * HID + h], acc);
    dp[gid] = acc;
}

#define MFMA16(a, bfv, c) __builtin_amdgcn_mfma_f32_16x16x32_bf16(a, bfv, c, 0, 0, 0)

// ---------------- main fused scores kernel: 64 rows x 512 cols, 8 waves,
// 2 blocks/CU (VGPR<=128, LDS 74KB) -> cross-block latency hiding (m114)
__global__ __launch_bounds__(512, 4) void scores_kernel(
    const float* __restrict__ enc, const float* __restrict__ cov,
    const unsigned short* __restrict__ Wt, const float* __restrict__ dp,
    const float* __restrict__ Wc, const float* __restrict__ vv,
    float* __restrict__ spart_out)
{
    extern __shared__ char smem[];
    unsigned short* BlS = (unsigned short*)smem;     // 2 bufs x 16384 shorts (32KB)
    char*  AlB   = smem + 65536;                     // 2 bufs x 4096 B
    float* cov_s = (float*)(smem + 73728);           // 64 floats
    float* sred  = (float*)(smem + 73984);           // 64 x 4 floats

    const int tid  = threadIdx.x;
    const int lane = tid & 63;
    const int wid  = tid >> 6;       // 0..7
    const int wm   = wid >> 2;       // 0..1 : 32-row half
    const int wn   = wid & 3;        // 0..3 : 128-col slice
    const int c15  = lane & 15;
    const int g4   = lane >> 4;      // 0..3

    // bid pairs: (m, half=0), (m, half=1) adjacent -> enc panel L3-hot on 2nd read
    const int bid  = blockIdx.x;
    const int half = bid & 1;
    const int m    = bid >> 1;                 // 0..2047
    const int b    = m >> 5;
    const int s0   = (m & 31) * BM;

    const float* Abase = enc + (size_t)(b * SEQ + s0) * EDIM;
    // A staging: threads 0..255, one (row, granule) 16B pack each
    const int arow = tid >> 2;                 // 0..63
    const int ag   = tid & 3;

    const unsigned short* Bsrc = Wt + half * 4096 + (size_t)tid * 8;

    f32x4a acc[2][8];
    #pragma unroll
    for (int mi = 0; mi < 2; ++mi)
        #pragma unroll
        for (int nj = 0; nj < 8; ++nj)
            #pragma unroll
            for (int r = 0; r < 4; ++r) acc[mi][nj][r] = 0.f;

    if (tid < BM) cov_s[tid] = cov[b * SEQ + s0 + tid];

    // prologue: stage k-step 0 into buffer 0
    {
        #pragma unroll
        for (int j = 0; j < 4; ++j)
            gload16(Bsrc + (size_t)j * 8192, BlS + j * 4096 + tid * 8);
        if (tid < 256) {
            const float* ap = Abase + (size_t)arow * EDIM + ag * 8;
            *(uint4*)(AlB + a_addr(arow, ag)) = pack8(ntload4(ap), ntload4(ap + 4));
        }
    }
    __syncthreads();

    for (int kk = 0; kk < KSTEPS; ++kk) {
        const int cur = kk & 1, nxt = cur ^ 1;
        const unsigned short* Bcur = BlS + cur * 16384;
        const char* Acur = AlB + cur * 4096;
        f32x4a a0n, a1n;

        if (kk + 1 < KSTEPS) {
            // issue next B tile (4 x 8KB contiguous granule-chunks -> linear LDS)
            const unsigned short* bs = Bsrc + (size_t)(kk + 1) * 32768;
            unsigned short* bd = BlS + nxt * 16384 + tid * 8;
            #pragma unroll
            for (int j = 0; j < 4; ++j)
                gload16(bs + (size_t)j * 8192, bd + j * 4096);
            if (tid < 256) {   // next A reg loads (NT: keep Wt L2-resident)
                const float* ap = Abase + (size_t)arow * EDIM + (kk + 1) * BK + ag * 8;
                a0n = ntload4(ap); a1n = ntload4(ap + 4);
            }
        }

        bf16x8 afr0 = *(const bf16x8*)(Acur + a_addr(wm * 32 + c15, g4));
        bf16x8 afr1 = *(const bf16x8*)(Acur + a_addr(wm * 32 + 16 + c15, g4));
        #pragma unroll
        for (int nj = 0; nj < 8; ++nj) {
            // granule chunk = 4096 shorts; h-entry = 8 shorts (bugfix from R8)
            bf16x8 bfr = *(const bf16x8*)(Bcur + (size_t)g4 * 4096 +
                                          (size_t)(wn * 128 + nj * 16 + c15) * 8);
            acc[0][nj] = MFMA16(afr0, bfr, acc[0][nj]);
            acc[1][nj] = MFMA16(afr1, bfr, acc[1][nj]);
        }

        if (kk + 1 < KSTEPS && tid < 256)
            *(uint4*)(AlB + nxt * 4096 + a_addr(arow, ag)) = pack8(a0n, a1n);
        __syncthreads();
    }

    // epilogue: + dec_proj + cov*W_c -> tanh -> * v, reduce this block's 512 cols
    float spart[2][4] = {{0.f,0.f,0.f,0.f},{0.f,0.f,0.f,0.f}};
    #pragma unroll
    for (int nj = 0; nj < 8; ++nj) {
        const int h = half * BN + wn * 128 + nj * 16 + c15;
        const float dv  = dp[b * HID + h];
        const float wcv = Wc[h];
        const float vvv = vv[h];
        #pragma unroll
        for (int mi = 0; mi < 2; ++mi) {
            #pragma unroll
            for (int r = 0; r < 4; ++r) {
                const int row = wm * 32 + mi * 16 + g4 * 4 + r;
                float pre = acc[mi][nj][r] + dv + cov_s[row] * wcv;
                float pc = fminf(pre, 20.0f);       // tanh(20)==1 in fp32
                float e2 = __expf(2.0f * pc);
                spart[mi][r] = fmaf((e2 - 1.0f) / (e2 + 1.0f), vvv, spart[mi][r]);
            }
        }
    }
    #pragma unroll
    for (int mi = 0; mi < 2; ++mi) {
        #pragma unroll
        for (int r = 0; r < 4; ++r) {
            float x = spart[mi][r];
            x += __shfl_xor(x, 1);
            x += __shfl_xor(x, 2);
            x += __shfl_xor(x, 4);
            x += __shfl_xor(x, 8);
            if (c15 == 0) sred[(wm * 32 + mi * 16 + g4 * 4 + r) * 4 + wn] = x;
        }
    }
    __syncthreads();
    if (tid < BM) {
        float s = sred[tid * 4] + sred[tid * 4 + 1] + sred[tid * 4 + 2] + sred[tid * 4 + 3];
        spart_out[(size_t)half * BS + b * SEQ + s0 + tid] = s;
    }
}

// ---------------- softmax + coverage_new (sums the two N-half partial scores)
__global__ void softmax_kernel(const float* __restrict__ spart,
                               const int* __restrict__ mask,
                               const float* __restrict__ cov,
                               float* __restrict__ out)
{
    __shared__ float red[8];
    int b = blockIdx.x, tid = threadIdx.x;   // 256 threads
    float vals[8];
    float mx = -1e30f;
    #pragma unroll
    for (int i = 0; i < 8; ++i) {
        int s = tid + i * 256;
        float sc = spart[b * SEQ + s] + spart[BS + b * SEQ + s];
        sc = (mask[b * SEQ + s] == 0) ? -10000.0f : sc;
        vals[i] = sc;
        mx = fmaxf(mx, sc);
    }
    for (int m = 1; m < 64; m <<= 1) mx = fmaxf(mx, __shfl_xor(mx, m));
    if ((tid & 63) == 0) red[tid >> 6] = mx;
    __syncthreads();
    mx = fmaxf(fmaxf(red[0], red[1]), fmaxf(red[2], red[3]));
    float sum = 0.f;
    #pragma unroll
    for (int i = 0; i < 8; ++i) { vals[i] = __expf(vals[i] - mx); sum += vals[i]; }
    for (int m = 1; m < 64; m <<= 1) sum += __shfl_xor(sum, m);
    if ((tid & 63) == 0) red[4 + (tid >> 6)] = sum;
    __syncthreads();
    sum = red[4] + red[5] + red[6] + red[7];
    float inv = 1.0f / sum;
    float* attn = out + BATCH * EDIM;
    float* covn = attn + BATCH * SEQ;
    #pragma unroll
    for (int i = 0; i < 8; ++i) {
        int s = tid + i * 256;
        float w = vals[i] * inv;
        attn[b * SEQ + s] = w;
        covn[b * SEQ + s] = cov[b * SEQ + s] + w;
    }
}

// ---------------- context partials: (b, e-slice, s-chunk) -> cpart
__global__ void context_partial_kernel(const float* __restrict__ enc,
                                       const float* __restrict__ attn,
                                       float* __restrict__ cpart)
{
    __shared__ float w_s[512];
    int bid = blockIdx.x;
    int sc = bid & 3;            // S-chunk of 512
    int e0 = ((bid >> 2) & 7) * 256;
    int b  = bid >> 5;
    int tid = threadIdx.x;
    w_s[tid] = attn[b * SEQ + sc * 512 + tid];
    w_s[tid + 256] = attn[b * SEQ + sc * 512 + 256 + tid];
    __syncthreads();
    const float* ep = enc + ((size_t)b * SEQ + sc * 512) * EDIM + e0 + tid;
    float acc = 0.f;
    #pragma unroll 8
    for (int s = 0; s < 512; ++s)
        acc = fmaf(w_s[s], __builtin_nontemporal_load(ep + (size_t)s * EDIM), acc);
    cpart[((size_t)sc * BATCH + b) * EDIM + e0 + tid] = acc;
}

__global__ void ctx_reduce_kernel(const float* __restrict__ cpart,
                                  float* __restrict__ ctx)
{
    int idx = blockIdx.x * 256 + threadIdx.x;     // 0 .. B*EDIM
    ctx[idx] = cpart[idx] + cpart[BATCH * EDIM + idx] +
               cpart[2 * BATCH * EDIM + idx] + cpart[3 * BATCH * EDIM + idx];
}

extern "C" void kernel_launch(void* const* d_in, const int* in_sizes, int n_in,
                              void* d_out, int out_size, void* d_ws, size_t ws_size,
                              hipStream_t stream) {
    const float* dec  = (const float*)d_in[0];
    const float* enc  = (const float*)d_in[1];
    const float* cov  = (const float*)d_in[2];
    const int*   mask = (const int*)d_in[3];
    const float* Wh   = (const float*)d_in[4];
    const float* Wd   = (const float*)d_in[5];
    const float* Wc   = (const float*)d_in[6];
    const float* v    = (const float*)d_in[7];
    float* out = (float*)d_out;

    unsigned short* Wt = (unsigned short*)d_ws;                        // 4 MiB bf16
    float* dp    = (float*)((char*)d_ws + (size_t)HID * EDIM * 2);     // 256 KiB
    float* spart = dp + BATCH * HID;                                   // 1 MiB (2 halves)
    float* cpart = spart + 2 * BS;                                     // 2 MiB

    (void)hipFuncSetAttribute((const void*)scores_kernel,
                              hipFuncAttributeMaxDynamicSharedMemorySize, SMEM_BYTES);

    wh_transpose_kernel<<<dim3(64 * 32), dim3(256), 0, stream>>>(Wh, Wt);
    dec_proj_kernel<<<dim3(BATCH * HID / 256), dim3(256), 0, stream>>>(dec, Wd, dp);
    scores_kernel<<<dim3((BS / BM) * 2), dim3(512), SMEM_BYTES, stream>>>(
        enc, cov, Wt, dp, Wc, v, spart);
    softmax_kernel<<<dim3(BATCH), dim3(256), 0, stream>>>(spart, mask, cov, out);
    context_partial_kernel<<<dim3(BATCH * 8 * 4), dim3(256), 0, stream>>>(
        enc, out + BATCH * EDIM, cpart);
    ctx_reduce_kernel<<<dim3(BATCH * EDIM / 256), dim3(256), 0, stream>>>(cpart, out);
}

// Round 10
// 1048.535 us; speedup vs baseline: 24.6559x; 1.0142x over previous
//
#include <hip/hip_runtime.h>
#include <hip/hip_bf16.h>
#include <stdint.h>

#define BATCH 64
#define SEQ   2048
#define HID   1024
#define EDIM  2048   // 2*HID

#define BM 64         // rows per block
#define BN 512        // cols per block (n-split = 2)
#define BK 32
#define KSTEPS (EDIM / BK)   // 64
#define BS (BATCH * SEQ)

typedef __bf16 bf16x8 __attribute__((ext_vector_type(8)));
typedef float  f32x4a __attribute__((ext_vector_type(4)));

__device__ __forceinline__ unsigned short f2bf(float x) {
    __hip_bfloat16 h = __float2bfloat16(x);
    return __builtin_bit_cast(unsigned short, h);
}

__device__ __forceinline__ uint4 pack8(f32x4a f0, f32x4a f1) {
    uint4 r;
    r.x = (unsigned)f2bf(f0.x) | ((unsigned)f2bf(f0.y) << 16);
    r.y = (unsigned)f2bf(f0.z) | ((unsigned)f2bf(f0.w) << 16);
    r.z = (unsigned)f2bf(f1.x) | ((unsigned)f2bf(f1.y) << 16);
    r.w = (unsigned)f2bf(f1.z) | ((unsigned)f2bf(f1.w) << 16);
    return r;
}

__device__ __forceinline__ f32x4a ntload4(const float* p) {
    return __builtin_nontemporal_load((const f32x4a*)p);
}

// A-tile LDS byte addr: 64 rows x 64B, granule slot XOR-swizzled
__device__ __forceinline__ int a_addr(int row, int g) {
    int slot = g ^ ((row & 3) ^ ((row >> 2) & 3));
    return (row << 6) + (slot << 4);
}

// ---------------- prep: W_h (EDIM x HID fp32) -> Wt bf16 granule-major:
// element (h,e) at Wt[(e>>3)*8192 + h*8 + (e&7)]  (fragment = 256B contiguous)
__global__ void wh_transpose_kernel(const float* __restrict__ Wh,
                                    unsigned short* __restrict__ Wt) {
    __shared__ float tile[32][33];
    int bx = blockIdx.x & 63;    // e-tile
    int by = blockIdx.x >> 6;    // h-tile
    int e0 = bx * 32, h0 = by * 32;
    int tx = threadIdx.x & 31, ty = threadIdx.x >> 5;   // 32 x 8
    #pragma unroll
    for (int i = 0; i < 4; ++i)
        tile[ty + 8 * i][tx] = Wh[(size_t)(e0 + ty + 8 * i) * HID + h0 + tx];
    __syncthreads();
    if (ty < 4) {
        uint4 wv;
        unsigned short* ws = (unsigned short*)&wv;
        #pragma unroll
        for (int j = 0; j < 8; ++j) ws[j] = f2bf(tile[ty * 8 + j][tx]);
        *(uint4*)&Wt[(size_t)((e0 >> 3) + ty) * 8192 + (size_t)(h0 + tx) * 8] = wv;
    }
}

// ---------------- prep: dec_proj = decoder_hidden @ W_d  (fp32, (B,HID))
__global__ void dec_proj_kernel(const float* __restrict__ dec,
                                const float* __restrict__ Wd,
                                float* __restrict__ dp) {
    int gid = blockIdx.x * 256 + threadIdx.x;
    int b = gid >> 10, h = gid & 1023;
    const float* dr = dec + b * HID;
    float acc = 0.f;
    #pragma unroll 4
    for (int k = 0; k < HID; ++k) acc = fmaf(dr[k], Wd[(size_t)k * HID + h], acc);
    dp[gid] = acc;
}

#define MFMA16(a, bfv, c) __builtin_amdgcn_mfma_f32_16x16x32_bf16(a, bfv, c, 0, 0, 0)

// ---------------- main fused scores kernel: 64 rows x 512 cols, 8 waves,
// B fragments global->reg from L2-resident Wt (no B LDS), A via tiny LDS dbuf.
// 2 blocks/CU (VGPR 128 total), LDS 10.5KB.
__global__ __launch_bounds__(512, 4) void scores_kernel(
    const float* __restrict__ enc, const float* __restrict__ cov,
    const unsigned short* __restrict__ Wt, const float* __restrict__ dp,
    const float* __restrict__ Wc, const float* __restrict__ vv,
    float* __restrict__ spart_out)
{
    __shared__ char Al[2][4096];       // A dbuf: 64 rows x 64B, swizzled
    __shared__ float cov_s[BM];
    __shared__ float sred[BM][8];

    const int tid  = threadIdx.x;
    const int lane = tid & 63;
    const int wid  = tid >> 6;       // 0..7 : 64-col slice
    const int c15  = lane & 15;
    const int g4   = lane >> 4;      // 0..3 : k-granule

    // bid pairs: (m, half=0/1) adjacent -> enc panel L3-hot on 2nd read
    const int bid  = blockIdx.x;
    const int half = bid & 1;
    const int m    = bid >> 1;                 // 0..2047
    const int b    = m >> 5;
    const int s0   = (m & 31) * BM;

    const float* Abase = enc + (size_t)(b * SEQ + s0) * EDIM;
    // A staging: threads 0..255, one (row, granule) 16B pack each
    const int arow = tid >> 2;                 // 0..63
    const int ag   = tid & 3;

    // per-lane B base: granule g4, h = half*512 + wid*64 + c15 (+16*nj via imm)
    const unsigned short* bptr =
        Wt + (size_t)g4 * 8192 + (size_t)(half * BN + wid * 64 + c15) * 8;

    f32x4a acc[4][4];
    #pragma unroll
    for (int mi = 0; mi < 4; ++mi)
        #pragma unroll
        for (int nj = 0; nj < 4; ++nj)
            #pragma unroll
            for (int r = 0; r < 4; ++r) acc[mi][nj][r] = 0.f;

    if (tid < BM) cov_s[tid] = cov[b * SEQ + s0 + tid];

    // prologue: stage A(0) into buffer 0
    if (tid < 256) {
        const float* ap = Abase + (size_t)arow * EDIM + ag * 8;
        *(uint4*)(Al[0] + a_addr(arow, ag)) = pack8(ntload4(ap), ntload4(ap + 4));
    }
    __syncthreads();

    for (int kk = 0; kk < KSTEPS; ++kk) {
        const int cur = kk & 1, nxt = cur ^ 1;

        // B fragments for this k-step straight from L2 (4 x 16B per lane)
        bf16x8 bfr[4];
        #pragma unroll
        for (int nj = 0; nj < 4; ++nj)
            bfr[nj] = *(const bf16x8*)(bptr + nj * 128);
        bptr += 4 * 8192;   // next k-step (4 granules)

        f32x4a a0n, a1n;
        if (kk + 1 < KSTEPS && tid < 256) {   // next A loads (NT: keep Wt in L2)
            const float* ap = Abase + (size_t)arow * EDIM + (kk + 1) * BK + ag * 8;
            a0n = ntload4(ap); a1n = ntload4(ap + 4);
        }

        bf16x8 afr[4];
        #pragma unroll
        for (int mi = 0; mi < 4; ++mi)
            afr[mi] = *(const bf16x8*)(Al[cur] + a_addr(mi * 16 + c15, g4));

        #pragma unroll
        for (int mi = 0; mi < 4; ++mi)
            #pragma unroll
            for (int nj = 0; nj < 4; ++nj)
                acc[mi][nj] = MFMA16(afr[mi], bfr[nj], acc[mi][nj]);

        if (kk + 1 < KSTEPS && tid < 256)
            *(uint4*)(Al[nxt] + a_addr(arow, ag)) = pack8(a0n, a1n);
        __syncthreads();
    }

    // epilogue: + dec_proj + cov*W_c -> tanh -> * v, reduce this block's 512 cols
    float spart[4][4];
    #pragma unroll
    for (int mi = 0; mi < 4; ++mi)
        #pragma unroll
        for (int r = 0; r < 4; ++r) spart[mi][r] = 0.f;

    #pragma unroll
    for (int nj = 0; nj < 4; ++nj) {
        const int h = half * BN + wid * 64 + nj * 16 + c15;
        const float dv  = dp[b * HID + h];
        const float wcv = Wc[h];
        const float vvv = vv[h];
        #pragma unroll
        for (int mi = 0; mi < 4; ++mi) {
            #pragma unroll
            for (int r = 0; r < 4; ++r) {
                const int row = mi * 16 + g4 * 4 + r;
                float pre = acc[mi][nj][r] + dv + cov_s[row] * wcv;
                float pc = fminf(pre, 20.0f);       // tanh(20)==1 in fp32
                float e2 = __expf(2.0f * pc);
                spart[mi][r] = fmaf((e2 - 1.0f) / (e2 + 1.0f), vvv, spart[mi][r]);
            }
        }
    }
    #pragma unroll
    for (int mi = 0; mi < 4; ++mi) {
        #pragma unroll
        for (int r = 0; r < 4; ++r) {
            float x = spart[mi][r];
            x += __shfl_xor(x, 1);
            x += __shfl_xor(x, 2);
            x += __shfl_xor(x, 4);
            x += __shfl_xor(x, 8);
            if (c15 == 0) sred[mi * 16 + g4 * 4 + r][wid] = x;
        }
    }
    __syncthreads();
    if (tid < BM) {
        float s = 0.f;
        #pragma unroll
        for (int w = 0; w < 8; ++w) s += sred[tid][w];
        spart_out[(size_t)half * BS + b * SEQ + s0 + tid] = s;
    }
}

// ---------------- softmax + coverage_new (sums the two N-half partial scores)
__global__ void softmax_kernel(const float* __restrict__ spart,
                               const int* __restrict__ mask,
                               const float* __restrict__ cov,
                               float* __restrict__ out)
{
    __shared__ float red[8];
    int b = blockIdx.x, tid = threadIdx.x;   // 256 threads
    float vals[8];
    float mx = -1e30f;
    #pragma unroll
    for (int i = 0; i < 8; ++i) {
        int s = tid + i * 256;
        float sc = spart[b * SEQ + s] + spart[BS + b * SEQ + s];
        sc = (mask[b * SEQ + s] == 0) ? -10000.0f : sc;
        vals[i] = sc;
        mx = fmaxf(mx, sc);
    }
    for (int m = 1; m < 64; m <<= 1) mx = fmaxf(mx, __shfl_xor(mx, m));
    if ((tid & 63) == 0) red[tid >> 6] = mx;
    __syncthreads();
    mx = fmaxf(fmaxf(red[0], red[1]), fmaxf(red[2], red[3]));
    float sum = 0.f;
    #pragma unroll
    for (int i = 0; i < 8; ++i) { vals[i] = __expf(vals[i] - mx); sum += vals[i]; }
    for (int m = 1; m < 64; m <<= 1) sum += __shfl_xor(sum, m);
    if ((tid & 63) == 0) red[4 + (tid >> 6)] = sum;
    __syncthreads();
    sum = red[4] + red[5] + red[6] + red[7];
    float inv = 1.0f / sum;
    float* attn = out + BATCH * EDIM;
    float* covn = attn + BATCH * SEQ;
    #pragma unroll
    for (int i = 0; i < 8; ++i) {
        int s = tid + i * 256;
        float w = vals[i] * inv;
        attn[b * SEQ + s] = w;
        covn[b * SEQ + s] = cov[b * SEQ + s] + w;
    }
}

// ---------------- context partials: (b, e-slice, s-chunk) -> cpart
__global__ void context_partial_kernel(const float* __restrict__ enc,
                                       const float* __restrict__ attn,
                                       float* __restrict__ cpart)
{
    __shared__ float w_s[512];
    int bid = blockIdx.x;
    int sc = bid & 3;            // S-chunk of 512
    int e0 = ((bid >> 2) & 7) * 256;
    int b  = bid >> 5;
    int tid = threadIdx.x;
    w_s[tid] = attn[b * SEQ + sc * 512 + tid];
    w_s[tid + 256] = attn[b * SEQ + sc * 512 + 256 + tid];
    __syncthreads();
    const float* ep = enc + ((size_t)b * SEQ + sc * 512) * EDIM + e0 + tid;
    float acc = 0.f;
    #pragma unroll 8
    for (int s = 0; s < 512; ++s)
        acc = fmaf(w_s[s], __builtin_nontemporal_load(ep + (size_t)s * EDIM), acc);
    cpart[((size_t)sc * BATCH + b) * EDIM + e0 + tid] = acc;
}

__global__ void ctx_reduce_kernel(const float* __restrict__ cpart,
                                  float* __restrict__ ctx)
{
    int idx = blockIdx.x * 256 + threadIdx.x;     // 0 .. B*EDIM
    ctx[idx] = cpart[idx] + cpart[BATCH * EDIM + idx] +
               cpart[2 * BATCH * EDIM + idx] + cpart[3 * BATCH * EDIM + idx];
}

extern "C" void kernel_launch(void* const* d_in, const int* in_sizes, int n_in,
                              void* d_out, int out_size, void* d_ws, size_t ws_size,
                              hipStream_t stream) {
    const float* dec  = (const float*)d_in[0];
    const float* enc  = (const float*)d_in[1];
    const float* cov  = (const float*)d_in[2];
    const int*   mask = (const int*)d_in[3];
    const float* Wh   = (const float*)d_in[4];
    const float* Wd   = (const float*)d_in[5];
    const float* Wc   = (const float*)d_in[6];
    const float* v    = (const float*)d_in[7];
    float* out = (float*)d_out;

    unsigned short* Wt = (unsigned short*)d_ws;                        // 4 MiB bf16
    float* dp    = (float*)((char*)d_ws + (size_t)HID * EDIM * 2);     // 256 KiB
    float* spart = dp + BATCH * HID;                                   // 1 MiB (2 halves)
    float* cpart = spart + 2 * BS;                                     // 2 MiB

    wh_transpose_kernel<<<dim3(64 * 32), dim3(256), 0, stream>>>(Wh, Wt);
    dec_proj_kernel<<<dim3(BATCH * HID / 256), dim3(256), 0, stream>>>(dec, Wd, dp);
    scores_kernel<<<dim3((BS / BM) * 2), dim3(512), 0, stream>>>(
        enc, cov, Wt, dp, Wc, v, spart);
    softmax_kernel<<<dim3(BATCH), dim3(256), 0, stream>>>(spart, mask, cov, out);
    context_partial_kernel<<<dim3(BATCH * 8 * 4), dim3(256), 0, stream>>>(
        enc, out + BATCH * EDIM, cpart);
    ctx_reduce_kernel<<<dim3(BATCH * EDIM / 256), dim3(256), 0, stream>>>(cpart, out);
}

// Round 11
// 1043.601 us; speedup vs baseline: 24.7725x; 1.0047x over previous
//
#include <hip/hip_runtime.h>
#include <hip/hip_bf16.h>
#include <stdint.h>

#define BATCH 64
#define SEQ   2048
#define HID   1024
#define EDIM  2048   // 2*HID

#define BM 64         // rows per block
#define BN 512        // cols per block (n-split = 2)
#define BK 32
#define KSTEPS (EDIM / BK)   // 64
#define BS (BATCH * SEQ)

typedef __bf16 bf16x8 __attribute__((ext_vector_type(8)));
typedef float  f32x4a __attribute__((ext_vector_type(4)));

__device__ __forceinline__ unsigned short f2bf(float x) {
    __hip_bfloat16 h = __float2bfloat16(x);
    return __builtin_bit_cast(unsigned short, h);
}

__device__ __forceinline__ uint4 pack8(f32x4a f0, f32x4a f1) {
    uint4 r;
    r.x = (unsigned)f2bf(f0.x) | ((unsigned)f2bf(f0.y) << 16);
    r.y = (unsigned)f2bf(f0.z) | ((unsigned)f2bf(f0.w) << 16);
    r.z = (unsigned)f2bf(f1.x) | ((unsigned)f2bf(f1.y) << 16);
    r.w = (unsigned)f2bf(f1.z) | ((unsigned)f2bf(f1.w) << 16);
    return r;
}

__device__ __forceinline__ uint2 pack4(f32x4a f) {
    uint2 r;
    r.x = (unsigned)f2bf(f.x) | ((unsigned)f2bf(f.y) << 16);
    r.y = (unsigned)f2bf(f.z) | ((unsigned)f2bf(f.w) << 16);
    return r;
}

__device__ __forceinline__ f32x4a ntload4(const float* p) {
    return __builtin_nontemporal_load((const f32x4a*)p);
}

// V0 A-tile LDS byte addr (R10): 64 rows x 64B, granule slot XOR-swizzled
__device__ __forceinline__ int a_addr(int row, int g) {
    int slot = g ^ ((row & 3) ^ ((row >> 2) & 3));
    return (row << 6) + (slot << 4);
}

// V1 A-tile addrs: write 8B chunks (chunk c ^= row&6 keeps 16B pairs intact),
// read b128 at granule g -> chunk pair 2*(g ^ ((row>>1)&3))
__device__ __forceinline__ int a_waddr1(int row, int c) {
    return (row << 6) + ((c ^ (row & 6)) << 3);
}
__device__ __forceinline__ int a_raddr1(int row, int g) {
    return (row << 6) + ((g ^ ((row >> 1) & 3)) << 4);
}

// ---------------- prep: W_h (EDIM x HID fp32) -> Wt bf16 granule-major:
// element (h,e) at Wt[(e>>3)*8192 + h*8 + (e&7)]  (fragment = 256B contiguous)
__global__ void wh_transpose_kernel(const float* __restrict__ Wh,
                                    unsigned short* __restrict__ Wt) {
    __shared__ float tile[32][33];
    int bx = blockIdx.x & 63;    // e-tile
    int by = blockIdx.x >> 6;    // h-tile
    int e0 = bx * 32, h0 = by * 32;
    int tx = threadIdx.x & 31, ty = threadIdx.x >> 5;   // 32 x 8
    #pragma unroll
    for (int i = 0; i < 4; ++i)
        tile[ty + 8 * i][tx] = Wh[(size_t)(e0 + ty + 8 * i) * HID + h0 + tx];
    __syncthreads();
    if (ty < 4) {
        uint4 wv;
        unsigned short* ws = (unsigned short*)&wv;
        #pragma unroll
        for (int j = 0; j < 8; ++j) ws[j] = f2bf(tile[ty * 8 + j][tx]);
        *(uint4*)&Wt[(size_t)((e0 >> 3) + ty) * 8192 + (size_t)(h0 + tx) * 8] = wv;
    }
}

// ---------------- prep: dec_proj = decoder_hidden @ W_d  (fp32, (B,HID))
__global__ void dec_proj_kernel(const float* __restrict__ dec,
                                const float* __restrict__ Wd,
                                float* __restrict__ dp) {
    int gid = blockIdx.x * 256 + threadIdx.x;
    int b = gid >> 10, h = gid & 1023;
    const float* dr = dec + b * HID;
    float acc = 0.f;
    #pragma unroll 4
    for (int k = 0; k < HID; ++k) acc = fmaf(dr[k], Wd[(size_t)k * HID + h], acc);
    dp[gid] = acc;
}

#define MFMA16(a, bfv, c) __builtin_amdgcn_mfma_f32_16x16x32_bf16(a, bfv, c, 0, 0, 0)

// Shared epilogue for both variants (acc layout identical)
__device__ __forceinline__ void scores_epilogue(
    f32x4a acc[4][4], const float* dp, const float* Wc, const float* vv,
    const float* cov_s, float sred[BM][8], float* spart_out,
    int b, int s0, int half, int wid, int c15, int g4, int tid)
{
    float spart[4][4];
    #pragma unroll
    for (int mi = 0; mi < 4; ++mi)
        #pragma unroll
        for (int r = 0; r < 4; ++r) spart[mi][r] = 0.f;

    #pragma unroll
    for (int nj = 0; nj < 4; ++nj) {
        const int h = half * BN + wid * 64 + nj * 16 + c15;
        const float dv  = dp[b * HID + h];
        const float wcv = Wc[h];
        const float vvv = vv[h];
        #pragma unroll
        for (int mi = 0; mi < 4; ++mi) {
            #pragma unroll
            for (int r = 0; r < 4; ++r) {
                const int row = mi * 16 + g4 * 4 + r;
                float pre = acc[mi][nj][r] + dv + cov_s[row] * wcv;
                float pc = fminf(pre, 20.0f);       // tanh(20)==1 in fp32
                float e2 = __expf(2.0f * pc);
                spart[mi][r] = fmaf((e2 - 1.0f) / (e2 + 1.0f), vvv, spart[mi][r]);
            }
        }
    }
    #pragma unroll
    for (int mi = 0; mi < 4; ++mi) {
        #pragma unroll
        for (int r = 0; r < 4; ++r) {
            float x = spart[mi][r];
            x += __shfl_xor(x, 1);
            x += __shfl_xor(x, 2);
            x += __shfl_xor(x, 4);
            x += __shfl_xor(x, 8);
            if (c15 == 0) sred[mi * 16 + g4 * 4 + r][wid] = x;
        }
    }
    __syncthreads();
    if (tid < BM) {
        float s = 0.f;
        #pragma unroll
        for (int w = 0; w < 8; ++w) s += sred[tid][w];
        spart_out[(size_t)half * BS + b * SEQ + s0 + tid] = s;
    }
}

// ---------------- V0 (control, R10 structure): dbuf + barrier/k-step
__global__ __launch_bounds__(512, 4) void scores_v0(
    const float* __restrict__ enc, const float* __restrict__ cov,
    const unsigned short* __restrict__ Wt, const float* __restrict__ dp,
    const float* __restrict__ Wc, const float* __restrict__ vv,
    float* __restrict__ spart_out)
{
    __shared__ char Al[2][4096];
    __shared__ float cov_s[BM];
    __shared__ float sred[BM][8];

    const int tid  = threadIdx.x;
    const int lane = tid & 63;
    const int wid  = tid >> 6;
    const int c15  = lane & 15;
    const int g4   = lane >> 4;

    const int bid  = blockIdx.x;
    const int half = bid & 1;
    const int m    = bid >> 1;                 // 0..1023
    const int b    = m >> 5;
    const int s0   = (m & 31) * BM;

    const float* Abase = enc + (size_t)(b * SEQ + s0) * EDIM;
    const int arow = tid >> 2;
    const int ag   = tid & 3;

    const unsigned short* bptr =
        Wt + (size_t)g4 * 8192 + (size_t)(half * BN + wid * 64 + c15) * 8;

    f32x4a acc[4][4];
    #pragma unroll
    for (int mi = 0; mi < 4; ++mi)
        #pragma unroll
        for (int nj = 0; nj < 4; ++nj)
            #pragma unroll
            for (int r = 0; r < 4; ++r) acc[mi][nj][r] = 0.f;

    if (tid < BM) cov_s[tid] = cov[b * SEQ + s0 + tid];

    if (tid < 256) {
        const float* ap = Abase + (size_t)arow * EDIM + ag * 8;
        *(uint4*)(Al[0] + a_addr(arow, ag)) = pack8(ntload4(ap), ntload4(ap + 4));
    }
    __syncthreads();

    for (int kk = 0; kk < KSTEPS; ++kk) {
        const int cur = kk & 1, nxt = cur ^ 1;

        bf16x8 bfr[4];
        #pragma unroll
        for (int nj = 0; nj < 4; ++nj)
            bfr[nj] = *(const bf16x8*)(bptr + nj * 128);
        bptr += 4 * 8192;

        f32x4a a0n, a1n;
        if (kk + 1 < KSTEPS && tid < 256) {
            const float* ap = Abase + (size_t)arow * EDIM + (kk + 1) * BK + ag * 8;
            a0n = ntload4(ap); a1n = ntload4(ap + 4);
        }

        bf16x8 afr[4];
        #pragma unroll
        for (int mi = 0; mi < 4; ++mi)
            afr[mi] = *(const bf16x8*)(Al[cur] + a_addr(mi * 16 + c15, g4));

        #pragma unroll
        for (int mi = 0; mi < 4; ++mi)
            #pragma unroll
            for (int nj = 0; nj < 4; ++nj)
                acc[mi][nj] = MFMA16(afr[mi], bfr[nj], acc[mi][nj]);

        if (kk + 1 < KSTEPS && tid < 256)
            *(uint4*)(Al[nxt] + a_addr(arow, ag)) = pack8(a0n, a1n);
        __syncthreads();
    }

    scores_epilogue(acc, dp, Wc, vv, cov_s, sred, spart_out,
                    b, s0, half, wid, c15, g4, tid);
}

// ---------------- V1 (test): 4-slot A ring, depth-2 prefetch, barrier/2 k-steps
__global__ __launch_bounds__(512, 4) void scores_v1(
    const float* __restrict__ enc, const float* __restrict__ cov,
    const unsigned short* __restrict__ Wt, const float* __restrict__ dp,
    const float* __restrict__ Wc, const float* __restrict__ vv,
    float* __restrict__ spart_out)
{
    __shared__ char Al[4][4096];     // 4-slot ring
    __shared__ float cov_s[BM];
    __shared__ float sred[BM][8];

    const int tid  = threadIdx.x;
    const int lane = tid & 63;
    const int wid  = tid >> 6;
    const int c15  = lane & 15;
    const int g4   = lane >> 4;

    const int bid  = blockIdx.x;
    const int half = bid & 1;
    const int m    = 1024 + (bid >> 1);        // upper half of m-tiles
    const int b    = m >> 5;
    const int s0   = (m & 31) * BM;

    const float* Abase = enc + (size_t)(b * SEQ + s0) * EDIM;
    // all 512 threads stage: one f32x4 (16B -> 8B bf16) per k-step
    const int arow = tid >> 3;                 // 0..63
    const int ac   = tid & 7;                  // chunk 0..7
    const float* ap0 = Abase + (size_t)arow * EDIM + ac * 4;
    const int wb = a_waddr1(arow, ac);

    const unsigned short* bptr =
        Wt + (size_t)g4 * 8192 + (size_t)(half * BN + wid * 64 + c15) * 8;

    f32x4a acc[4][4];
    #pragma unroll
    for (int mi = 0; mi < 4; ++mi)
        #pragma unroll
        for (int nj = 0; nj < 4; ++nj)
            #pragma unroll
            for (int r = 0; r < 4; ++r) acc[mi][nj][r] = 0.f;

    if (tid < BM) cov_s[tid] = cov[b * SEQ + s0 + tid];

    // prologue: slots 0,1 filled; A(2),A(3) in flight in regs
    f32x4a aL0, aL1;
    {
        f32x4a t0 = ntload4(ap0);
        f32x4a t1 = ntload4(ap0 + 32);
        *(uint2*)(Al[0] + wb) = pack4(t0);
        *(uint2*)(Al[1] + wb) = pack4(t1);
        aL0 = ntload4(ap0 + 64);
        aL1 = ntload4(ap0 + 96);
    }
    __syncthreads();

    for (int kk4 = 0; kk4 < KSTEPS; kk4 += 4) {
        #pragma unroll
        for (int u = 0; u < 4; ++u) {
            const int kk = kk4 + u;

            bf16x8 bfr[4];
            #pragma unroll
            for (int nj = 0; nj < 4; ++nj)
                bfr[nj] = *(const bf16x8*)(bptr + (size_t)kk * 32768 + nj * 128);

            bf16x8 afr[4];
            #pragma unroll
            for (int mi = 0; mi < 4; ++mi)
                afr[mi] = *(const bf16x8*)(Al[u] + a_raddr1(mi * 16 + c15, g4));

            #pragma unroll
            for (int mi = 0; mi < 4; ++mi)
                #pragma unroll
                for (int nj = 0; nj < 4; ++nj)
                    acc[mi][nj] = MFMA16(afr[mi], bfr[nj], acc[mi][nj]);

            if (kk < KSTEPS - 2) {
                // write A(kk+2) (loaded 2 steps ago) into slot (u+2)&3
                if (u & 1) {
                    *(uint2*)(Al[(u + 2) & 3] + wb) = pack4(aL1);
                    if (kk < KSTEPS - 4) aL1 = ntload4(ap0 + (kk + 4) * BK);
                } else {
                    *(uint2*)(Al[(u + 2) & 3] + wb) = pack4(aL0);
                    if (kk < KSTEPS - 4) aL0 = ntload4(ap0 + (kk + 4) * BK);
                }
            }
            if (u & 1) __syncthreads();   // barrier every 2 k-steps
        }
    }

    scores_epilogue(acc, dp, Wc, vv, cov_s, sred, spart_out,
                    b, s0, half, wid, c15, g4, tid);
}

// ---------------- softmax + coverage_new (sums the two N-half partial scores)
__global__ void softmax_kernel(const float* __restrict__ spart,
                               const int* __restrict__ mask,
                               const float* __restrict__ cov,
                               float* __restrict__ out)
{
    __shared__ float red[8];
    int b = blockIdx.x, tid = threadIdx.x;   // 256 threads
    float vals[8];
    float mx = -1e30f;
    #pragma unroll
    for (int i = 0; i < 8; ++i) {
        int s = tid + i * 256;
        float sc = spart[b * SEQ + s] + spart[BS + b * SEQ + s];
        sc = (mask[b * SEQ + s] == 0) ? -10000.0f : sc;
        vals[i] = sc;
        mx = fmaxf(mx, sc);
    }
    for (int m = 1; m < 64; m <<= 1) mx = fmaxf(mx, __shfl_xor(mx, m));
    if ((tid & 63) == 0) red[tid >> 6] = mx;
    __syncthreads();
    mx = fmaxf(fmaxf(red[0], red[1]), fmaxf(red[2], red[3]));
    float sum = 0.f;
    #pragma unroll
    for (int i = 0; i < 8; ++i) { vals[i] = __expf(vals[i] - mx); sum += vals[i]; }
    for (int m = 1; m < 64; m <<= 1) sum += __shfl_xor(sum, m);
    if ((tid & 63) == 0) red[4 + (tid >> 6)] = sum;
    __syncthreads();
    sum = red[4] + red[5] + red[6] + red[7];
    float inv = 1.0f / sum;
    float* attn = out + BATCH * EDIM;
    float* covn = attn + BATCH * SEQ;
    #pragma unroll
    for (int i = 0; i < 8; ++i) {
        int s = tid + i * 256;
        float w = vals[i] * inv;
        attn[b * SEQ + s] = w;
        covn[b * SEQ + s] = cov[b * SEQ + s] + w;
    }
}

// ---------------- context partials: (b, e-slice, s-chunk) -> cpart
__global__ void context_partial_kernel(const float* __restrict__ enc,
                                       const float* __restrict__ attn,
                                       float* __restrict__ cpart)
{
    __shared__ float w_s[512];
    int bid = blockIdx.x;
    int sc = bid & 3;            // S-chunk of 512
    int e0 = ((bid >> 2) & 7) * 256;
    int b  = bid >> 5;
    int tid = threadIdx.x;
    w_s[tid] = attn[b * SEQ + sc * 512 + tid];
    w_s[tid + 256] = attn[b * SEQ + sc * 512 + 256 + tid];
    __syncthreads();
    const float* ep = enc + ((size_t)b * SEQ + sc * 512) * EDIM + e0 + tid;
    float acc = 0.f;
    #pragma unroll 8
    for (int s = 0; s < 512; ++s)
        acc = fmaf(w_s[s], __builtin_nontemporal_load(ep + (size_t)s * EDIM), acc);
    cpart[((size_t)sc * BATCH + b) * EDIM + e0 + tid] = acc;
}

__global__ void ctx_reduce_kernel(const float* __restrict__ cpart,
                                  float* __restrict__ ctx)
{
    int idx = blockIdx.x * 256 + threadIdx.x;     // 0 .. B*EDIM
    ctx[idx] = cpart[idx] + cpart[BATCH * EDIM + idx] +
               cpart[2 * BATCH * EDIM + idx] + cpart[3 * BATCH * EDIM + idx];
}

extern "C" void kernel_launch(void* const* d_in, const int* in_sizes, int n_in,
                              void* d_out, int out_size, void* d_ws, size_t ws_size,
                              hipStream_t stream) {
    const float* dec  = (const float*)d_in[0];
    const float* enc  = (const float*)d_in[1];
    const float* cov  = (const float*)d_in[2];
    const int*   mask = (const int*)d_in[3];
    const float* Wh   = (const float*)d_in[4];
    const float* Wd   = (const float*)d_in[5];
    const float* Wc   = (const float*)d_in[6];
    const float* v    = (const float*)d_in[7];
    float* out = (float*)d_out;

    unsigned short* Wt = (unsigned short*)d_ws;                        // 4 MiB bf16
    float* dp    = (float*)((char*)d_ws + (size_t)HID * EDIM * 2);     // 256 KiB
    float* spart = dp + BATCH * HID;                                   // 1 MiB (2 halves)
    float* cpart = spart + 2 * BS;                                     // 2 MiB

    wh_transpose_kernel<<<dim3(64 * 32), dim3(256), 0, stream>>>(Wh, Wt);
    dec_proj_kernel<<<dim3(BATCH * HID / 256), dim3(256), 0, stream>>>(dec, Wd, dp);
    // A/B split: V0 handles m-tiles [0,1024), V1 handles [1024,2048)
    scores_v0<<<dim3(2048), dim3(512), 0, stream>>>(enc, cov, Wt, dp, Wc, v, spart);
    scores_v1<<<dim3(2048), dim3(512), 0, stream>>>(enc, cov, Wt, dp, Wc, v, spart);
    softmax_kernel<<<dim3(BATCH), dim3(256), 0, stream>>>(spart, mask, cov, out);
    context_partial_kernel<<<dim3(BATCH * 8 * 4), dim3(256), 0, stream>>>(
        enc, out + BATCH * EDIM, cpart);
    ctx_reduce_kernel<<<dim3(BATCH * EDIM / 256), dim3(256), 0, stream>>>(cpart, out);
}